// Round 4
// baseline (322.253 us; speedup 1.0000x reference)
//
#include <hip/hip_runtime.h>
#include <math.h>

typedef _Float16 half8  __attribute__((ext_vector_type(8)));
typedef _Float16 half4  __attribute__((ext_vector_type(4)));
typedef __fp16   f16x2  __attribute__((ext_vector_type(2)));
typedef float    floatx4 __attribute__((ext_vector_type(4)));

#define B_   2
#define L_   8192
#define H_   16
#define D_   64
#define C_   1024
#define NC_  8
#define HD_  1024             // global row stride in floats
#define LOG2B 0.41524101186098314f   // log2(10000)/32
#define LOG2E 1.4426950408889634f
#define DTHR  8.0f            // defer-rescale threshold (log2 units): P <= 2^8, safe in f16
#define NTILE 8192            // 2*16*8*32 (b,h,n,kt) K/V tiles in workspace

__device__ __forceinline__ float fast_exp2(float x) {
#if __has_builtin(__builtin_amdgcn_exp2f)
    return __builtin_amdgcn_exp2f(x);
#else
    return exp2f(x);
#endif
}

__device__ __forceinline__ unsigned pk16(float a, float b) {
    f16x2 r = __builtin_amdgcn_cvt_pkrtz(a, b);   // v_cvt_pkrtz_f16_f32
    return __builtin_bit_cast(unsigned, r);
}

__device__ __forceinline__ float rormax16(float v) {
    int x;
    x = __builtin_amdgcn_mov_dpp(__float_as_int(v), 0x121, 0xf, 0xf, true); v = fmaxf(v, __int_as_float(x));
    x = __builtin_amdgcn_mov_dpp(__float_as_int(v), 0x122, 0xf, 0xf, true); v = fmaxf(v, __int_as_float(x));
    x = __builtin_amdgcn_mov_dpp(__float_as_int(v), 0x124, 0xf, 0xf, true); v = fmaxf(v, __int_as_float(x));
    x = __builtin_amdgcn_mov_dpp(__float_as_int(v), 0x128, 0xf, 0xf, true); v = fmaxf(v, __int_as_float(x));
    return v;
}

// ============================ pass 1: prep ============================
// One block per (b,h,n,kt) tile. Writes to workspace:
//   K_rope f16 tiles [kk=32][d=64] linear, 4 KB each   (RoPE applied once, not 4x per j)
//   V^T    f16 tiles [dv=64][kk=32] linear, 4 KB each
__global__ __launch_bounds__(256, 2)
void prep_v6(const float* __restrict__ kg, const float* __restrict__ vg,
             const int* __restrict__ sidx, _Float16* __restrict__ ws)
{
    const int bid = blockIdx.x;          // [b][h][n][kt]
    const int kt = bid & 31;
    const int n  = (bid >> 5) & 7;
    const int h  = (bid >> 8) & 15;
    const int b  = bid >> 12;
    const int t  = threadIdx.x;

    const long gk = ((long)b * L_ + (long)n * C_ + (long)kt * 32) * HD_ + (long)h * D_;
    _Float16* Kt = ws + (long)bid * 2048;
    _Float16* Vt = ws + (long)NTILE * 2048 + (long)bid * 2048;

    // ---- K RoPE: 32 rows x 8 threads, 4 d each (both halves) ----
    {
        const int kk = t >> 3;
        const int sc = (t & 7) * 4;
        const float pos = (float)(sidx[0] + n * C_ + kt * 32 + kk);
        const float* kp = kg + gk + (long)kk * HD_ + sc;
        float4 f0 = *(const float4*)kp;
        float4 f1 = *(const float4*)(kp + 32);
        float ka[4] = {f0.x,f0.y,f0.z,f0.w};
        float kc[4] = {f1.x,f1.y,f1.z,f1.w};
        half4 o0, o1;
        #pragma unroll
        for (int i = 0; i < 4; ++i) {
            float invf = fast_exp2(-(float)(sc + i) * LOG2B);
            float sn, cs; __sincosf(pos * invf, &sn, &cs);
            o0[i] = (_Float16)(ka[i] * cs - kc[i] * sn);
            o1[i] = (_Float16)(kc[i] * cs + ka[i] * sn);
        }
        *(half4*)(Kt + kk * 64 + sc)      = o0;
        *(half4*)(Kt + kk * 64 + sc + 32) = o1;
    }

    // ---- V transpose: wave wv handles kk rows wv*8..wv*8+7, lane = dv ----
    {
        const int wv = t >> 6;
        const int dv = t & 63;
        const float* vp = vg + gk + (long)(wv * 8) * HD_ + dv;
        float x[8];
        #pragma unroll
        for (int i = 0; i < 8; ++i) x[i] = vp[(long)i * HD_];
        #pragma unroll
        for (int q = 0; q < 2; ++q) {
            half4 pkv;
            #pragma unroll
            for (int i = 0; i < 4; ++i) pkv[i] = (_Float16)x[q * 4 + i];
            *(half4*)(Vt + dv * 32 + wv * 8 + q * 4) = pkv;
        }
    }
}

// ============================ pass 2: attention ============================
// NOTE: min-waves hint MUST stay at 2. (256,4) forced 64-VGPR budget and
// spilled the accumulators (Round 2: WRITE 65MB->1.24GB, dur 165->682us).
__global__ __launch_bounds__(256, 2)
void attn_v6(const float* __restrict__ qg, const int* __restrict__ sidx,
             const _Float16* __restrict__ ws, float* __restrict__ outg)
{
    // LDS tiles, linear layouts + XOR swizzle (both writer & reader apply it):
    //   KT [kk=32][d=64] f16, rows 128B: byte ^= (kk&7)<<4  -> fragment b128 reads conflict-free
    //   VT [dv=64][kk=32] f16, rows 64B: byte ^= ((dv>>1)&3)<<4 -> 2-way (free)
    __shared__ __align__(16) _Float16 KT[2048];
    __shared__ __align__(16) _Float16 VT[2048];
    __shared__ __align__(16) _Float16 Pt[4][32 * 16];    // per-wave P^T slab [k][q]

    const int t  = threadIdx.x;
    const int w  = t >> 6;         // wave 0..3
    const int lg = (t >> 4) & 3;   // 16-lane group
    const int ln = t & 15;

    const int bid = blockIdx.x;
    // j in SLOWEST bits: CU c gets the four j-variants of ONE (b,n,h) ->
    // per-CU work balanced and K/V tiles shared via L1/L2 (R3: FETCH 270->253MB).
    const int j   = bid >> 8;
    const int grp = bid & 255;
    const int h   = grp & 15;
    const int n   = (grp >> 4) & 7;
    const int b   = grp >> 7;

    const int p0   = sidx[0] + n * C_;
    const int qoff = j * 64 + w * 16;

    const long bhbase = ((long)b * L_ + (long)n * C_) * HD_ + (long)h * D_;
    const int  tix    = (b * H_ + h) * NC_ + n;          // (b,h,n) tile-group index
    const _Float16* ktiles = ws + (long)tix * 32 * 2048;
    const _Float16* vtiles = ws + (long)NTILE * 2048 + (long)tix * 32 * 2048;

    // ---- Q fragments (A-layout) per strip, RoPE'd, f16, pre-scaled by log2(e) ----
    half8 aq[4][2];
    const int d0 = lg * 8;
    #pragma unroll
    for (int s = 0; s < 4; ++s) {
        const int qr = s * 256 + qoff + ln;
        const float* qp = qg + bhbase + (long)qr * HD_;
        float4 f0 = *(const float4*)(qp + d0);
        float4 f1 = *(const float4*)(qp + d0 + 4);
        float4 g0 = *(const float4*)(qp + d0 + 32);
        float4 g1 = *(const float4*)(qp + d0 + 36);
        float x[8] = {f0.x,f0.y,f0.z,f0.w,f1.x,f1.y,f1.z,f1.w};
        float y[8] = {g0.x,g0.y,g0.z,g0.w,g1.x,g1.y,g1.z,g1.w};
        const float pos = (float)(p0 + qr);
        #pragma unroll
        for (int jj = 0; jj < 8; ++jj) {
            float invf = fast_exp2(-(float)(d0 + jj) * LOG2B);
            float sn, cs; __sincosf(pos * invf, &sn, &cs);
            aq[s][0][jj] = (_Float16)((x[jj] * cs - y[jj] * sn) * LOG2E);
            aq[s][1][jj] = (_Float16)((y[jj] * cs + x[jj] * sn) * LOG2E);
        }
    }

    // ---- accumulators ----
    floatx4 O[4][4];
    floatx4 Ol[4];
    float   mr[4][4];
    #pragma unroll
    for (int s = 0; s < 4; ++s) {
        Ol[s] = (floatx4){0.f,0.f,0.f,0.f};
        #pragma unroll
        for (int dt = 0; dt < 4; ++dt) O[s][dt] = (floatx4){0.f,0.f,0.f,0.f};
        #pragma unroll
        for (int r = 0; r < 4; ++r) mr[s][r] = -1e30f;
    }
    half8 bones;
    #pragma unroll
    for (int jj = 0; jj < 8; ++jj) bones[jj] = (_Float16)1.0f;

    // ---- staging roles (pure copy now; RoPE/transpose moved to pass 1) ----
    const int skk = t >> 3;             // K row 0..31
    const int sdc = (t & 7) * 8;        // K col (f16), 8 per thread
    const int svd = t >> 2;             // V row (dv) 0..63
    const int svk = (t & 3) * 8;        // V col (f16)
    const int kwb = skk * 128 + ((sdc * 2) ^ ((skk & 7) << 4));          // swizzled K write byte
    const int vwb = svd * 64  + ((svk * 2) ^ (((svd >> 1) & 3) << 4));   // swizzled V write byte

    const int NKT = ((831 + j * 64) >> 5) + 1;
    int nkt_s[4];
    #pragma unroll
    for (int s = 0; s < 4; ++s) nkt_s[s] = ((s * 256 + qoff + 15) >> 5) + 1;

    // per-lane address for the hardware transpose-read of P^T
    const unsigned trad = (unsigned)(unsigned long long)(uintptr_t)(&Pt[w][0])
                        + 8u * (unsigned)ln + 256u * (unsigned)lg;

    // ---- prefetch tile 0 (2 x 16B per thread) ----
    half8 kreg = *(const half8*)(ktiles + (long)skk * 64 + sdc);
    half8 vreg = *(const half8*)(vtiles + (long)svd * 32 + svk);

    for (int kt = 0; kt < NKT; ++kt) {
        const int kb0 = kt * 32;
        __syncthreads();   // previous tile fully consumed
        *(half8*)((char*)KT + kwb) = kreg;
        *(half8*)((char*)VT + vwb) = vreg;
        if (kt + 1 < NKT) {
            const _Float16* kn = ktiles + (long)(kt + 1) * 2048;
            const _Float16* vn = vtiles + (long)(kt + 1) * 2048;
            kreg = *(const half8*)(kn + (long)skk * 64 + sdc);
            vreg = *(const half8*)(vn + (long)svd * 32 + svk);
        }
        __syncthreads();   // tile visible

        // ---- fragments shared across strips (swizzled reads, conflict-free) ----
        half8 bk0[2], bk1[2], bv[4];
        #pragma unroll
        for (int ct = 0; ct < 2; ++ct) {
            const int row = ct * 16 + ln;
            const char* base = (const char*)KT + row * 128;
            bk0[ct] = *(const half8*)(base + ((lg * 16)      ^ ((row & 7) << 4)));
            bk1[ct] = *(const half8*)(base + ((64 + lg * 16) ^ ((row & 7) << 4)));
        }
        #pragma unroll
        for (int dt = 0; dt < 4; ++dt) {
            const int dv = dt * 16 + ln;
            bv[dt] = *(const half8*)((const char*)VT + dv * 64 + ((lg * 16) ^ (((dv >> 1) & 3) << 4)));
        }

        #pragma unroll
        for (int s = 0; s < 4; ++s) {
            if (kt >= nkt_s[s]) continue;          // wave-uniform
            const int qs = s * 256 + qoff;

            floatx4 sacc[2];
            #pragma unroll
            for (int ct = 0; ct < 2; ++ct) {
                floatx4 acc = (floatx4){0.f,0.f,0.f,0.f};
                acc = __builtin_amdgcn_mfma_f32_16x16x32_f16(aq[s][0], bk0[ct], acc, 0, 0, 0);
                acc = __builtin_amdgcn_mfma_f32_16x16x32_f16(aq[s][1], bk1[ct], acc, 0, 0, 0);
                sacc[ct] = acc;
            }
            if (kb0 + 31 > qs) {                   // diagonal tile: mask
                #pragma unroll
                for (int ct = 0; ct < 2; ++ct) {
                    const int kkc = kb0 + ct * 16 + ln;
                    #pragma unroll
                    for (int r = 0; r < 4; ++r)
                        if (kkc > qs + lg * 4 + r) sacc[ct][r] = -1e30f;
                }
            }

            // ---- deferred-max online softmax (log2 domain) ----
            float tm[4];
            int grow = 0;
            #pragma unroll
            for (int r = 0; r < 4; ++r) {
                tm[r] = rormax16(fmaxf(sacc[0][r], sacc[1][r]));
                grow |= (tm[r] > mr[s][r] + DTHR) ? 1 : 0;
            }
            if (__any(grow)) {
                #pragma unroll
                for (int r = 0; r < 4; ++r) {
                    float mnew  = fmaxf(mr[s][r], tm[r]);
                    float alpha = fast_exp2(mr[s][r] - mnew);
                    mr[s][r] = mnew;
                    Ol[s][r] *= alpha;
                    #pragma unroll
                    for (int dt = 0; dt < 4; ++dt) O[s][dt][r] *= alpha;
                }
            }

            // ---- P -> f16 pairs, stored TRANSPOSED [k][q] ----
            uint2 wa, wb;
            wa.x = pk16(fast_exp2(sacc[0][0] - mr[s][0]), fast_exp2(sacc[0][1] - mr[s][1]));
            wa.y = pk16(fast_exp2(sacc[0][2] - mr[s][2]), fast_exp2(sacc[0][3] - mr[s][3]));
            wb.x = pk16(fast_exp2(sacc[1][0] - mr[s][0]), fast_exp2(sacc[1][1] - mr[s][1]));
            wb.y = pk16(fast_exp2(sacc[1][2] - mr[s][2]), fast_exp2(sacc[1][3] - mr[s][3]));
            *(uint2*)(&Pt[w][ ln       * 16 + lg * 4]) = wa;
            *(uint2*)(&Pt[w][(16 + ln) * 16 + lg * 4]) = wb;
            asm volatile("s_waitcnt lgkmcnt(0)" ::: "memory");
            half4 tlo, thi;
            asm volatile("ds_read_b64_tr_b16 %0, %2\n\t"
                         "ds_read_b64_tr_b16 %1, %2 offset:128"
                         : "=&v"(tlo), "=&v"(thi) : "v"(trad));
            asm volatile("s_waitcnt lgkmcnt(0)" ::: "memory");
            __builtin_amdgcn_sched_barrier(0);
            half8 ap = __builtin_shufflevector(tlo, thi, 0, 1, 2, 3, 4, 5, 6, 7);

            #pragma unroll
            for (int dt = 0; dt < 4; ++dt)
                O[s][dt] = __builtin_amdgcn_mfma_f32_16x16x32_f16(ap, bv[dt], O[s][dt], 0, 0, 0);
            Ol[s] = __builtin_amdgcn_mfma_f32_16x16x32_f16(ap, bones, Ol[s], 0, 0, 0);
        }
    }

    // ---- epilogue ----
    #pragma unroll
    for (int s = 0; s < 4; ++s) {
        const int qs = s * 256 + qoff;
        float inv[4];
        #pragma unroll
        for (int r = 0; r < 4; ++r) inv[r] = 1.0f / Ol[s][r];
        #pragma unroll
        for (int dt = 0; dt < 4; ++dt) {
            #pragma unroll
            for (int r = 0; r < 4; ++r) {
                const int qr = qs + lg * 4 + r;
                outg[bhbase + (long)qr * HD_ + dt * 16 + ln] = O[s][dt][r] * inv[r];
            }
        }
    }
}

extern "C" void kernel_launch(void* const* d_in, const int* in_sizes, int n_in,
                              void* d_out, int out_size, void* d_ws, size_t ws_size,
                              hipStream_t stream) {
    const float* q    = (const float*)d_in[0];
    const float* k    = (const float*)d_in[1];
    const float* v    = (const float*)d_in[2];
    const int*   sidx = (const int*)d_in[3];
    float*       out  = (float*)d_out;
    _Float16*    ws   = (_Float16*)d_ws;   // needs 64 MB (2 x 8192 tiles x 4 KB)

    dim3 block(256);
    prep_v6<<<dim3(NTILE), block, 0, stream>>>(k, v, sidx, ws);
    attn_v6<<<dim3(B_ * NC_ * H_ * 4), block, 0, stream>>>(q, sidx, ws, out);
}

// Round 5
// 304.380 us; speedup vs baseline: 1.0587x; 1.0587x over previous
//
#include <hip/hip_runtime.h>
#include <math.h>

typedef _Float16 half8  __attribute__((ext_vector_type(8)));
typedef _Float16 half4  __attribute__((ext_vector_type(4)));
typedef __fp16   f16x2  __attribute__((ext_vector_type(2)));
typedef float    floatx4 __attribute__((ext_vector_type(4)));
typedef int      int4v  __attribute__((ext_vector_type(4)));

#define B_   2
#define L_   8192
#define H_   16
#define D_   64
#define C_   1024
#define NC_  8
#define HD_  1024             // global row stride in floats
#define LOG2B 0.41524101186098314f   // log2(10000)/32
#define LOG2E 1.4426950408889634f
#define DTHR  8.0f            // defer-rescale threshold (log2 units): P <= 2^8, safe in f16
#define NTILE 8192            // 2*16*8*32 (b,h,n,kt) K/V tiles in workspace

__device__ __forceinline__ float fast_exp2(float x) {
#if __has_builtin(__builtin_amdgcn_exp2f)
    return __builtin_amdgcn_exp2f(x);
#else
    return exp2f(x);
#endif
}

__device__ __forceinline__ int pk16(float a, float b) {
    f16x2 r = __builtin_amdgcn_cvt_pkrtz(a, b);   // v_cvt_pkrtz_f16_f32
    return __builtin_bit_cast(int, r);
}

// ============================ pass 1: prep ============================
// One block per (b,h,n,kt) tile:
//   K_rope f16 [kk=32][d=64] linear, 4 KB  (RoPE applied once, not 8x per j)
//   V^T    f16 [dv=64][kk=32] linear, 4 KB (each thread writes one contiguous 16B)
__global__ __launch_bounds__(256, 2)
void prep_v7(const float* __restrict__ kg, const float* __restrict__ vg,
             const int* __restrict__ sidx, _Float16* __restrict__ ws)
{
    const int bid = blockIdx.x;          // [b][h][n][kt]
    const int kt = bid & 31;
    const int n  = (bid >> 5) & 7;
    const int h  = (bid >> 8) & 15;
    const int b  = bid >> 12;
    const int t  = threadIdx.x;

    const long gk = ((long)b * L_ + (long)n * C_ + (long)kt * 32) * HD_ + (long)h * D_;
    _Float16* Kt = ws + (long)bid * 2048;
    _Float16* Vt = ws + (long)NTILE * 2048 + (long)bid * 2048;

    // ---- K RoPE: 32 rows x 8 threads, 4 d each (both halves) ----
    {
        const int kk = t >> 3;
        const int sc = (t & 7) * 4;
        const float pos = (float)(sidx[0] + n * C_ + kt * 32 + kk);
        const float* kp = kg + gk + (long)kk * HD_ + sc;
        float4 f0 = *(const float4*)kp;
        float4 f1 = *(const float4*)(kp + 32);
        float ka[4] = {f0.x,f0.y,f0.z,f0.w};
        float kc[4] = {f1.x,f1.y,f1.z,f1.w};
        half4 o0, o1;
        #pragma unroll
        for (int i = 0; i < 4; ++i) {
            float invf = fast_exp2(-(float)(sc + i) * LOG2B);
            float sn, cs; __sincosf(pos * invf, &sn, &cs);
            o0[i] = (_Float16)(ka[i] * cs - kc[i] * sn);
            o1[i] = (_Float16)(kc[i] * cs + ka[i] * sn);
        }
        *(half4*)(Kt + kk * 64 + sc)      = o0;
        *(half4*)(Kt + kk * 64 + sc + 32) = o1;
    }

    // ---- V transpose: thread t owns Vt halves [t*8 .. t*8+7] (coalesced 16B write) ----
    {
        const int dv = t >> 2;
        const int k0 = (t & 3) * 8;
        const float* vp = vg + gk + (long)k0 * HD_ + dv;
        half8 o;
        #pragma unroll
        for (int i = 0; i < 8; ++i) o[i] = (_Float16)vp[(long)i * HD_];
        *(half8*)(Vt + t * 8) = o;
    }
}

// ============================ pass 2: attention ============================
// Swapped-operand QK^T (scores C[k][q=ln]) -> softmax row is lane-local+lg-spread:
// max/sum via fmax tree + ds_swizzle(xor16) + ds_bpermute(xor32); P^T -> PV
// A-fragment via 8x ds_bpermute (no LDS slab, no tr_read, no ones-MFMA).
// 2048 blocks x 2 strips: halves accumulator state -> target 3-4 blocks/CU.
// NOTE: min-waves hint MUST stay at 2 ((256,4) spilled accums in R2: dur 682us).
__global__ __launch_bounds__(256, 2)
void attn_v7(const float* __restrict__ qg, const int* __restrict__ sidx,
             const _Float16* __restrict__ ws, float* __restrict__ outg)
{
    // LDS tiles, linear + XOR swizzle (writer & reader both apply):
    //   KT [kk=32][d=64] f16, rows 128B: byte ^= (kk&7)<<4
    //   VT [dv=64][kk=32] f16, rows 64B: byte ^= ((dv>>1)&3)<<4
    __shared__ __align__(16) _Float16 KT[2048];
    __shared__ __align__(16) _Float16 VT[2048];

    const int t  = threadIdx.x;
    const int w  = t >> 6;         // wave 0..3
    const int lg = (t >> 4) & 3;   // 16-lane group
    const int ln = t & 15;

    const int bid = blockIdx.x;
    // j in SLOWEST bits: CU c gets the eight j-variants of ONE (b,n,h) ->
    // per-CU work balanced, K/V tiles shared via L1/L2.
    const int j   = bid >> 8;      // 0..7
    const int grp = bid & 255;
    const int h   = grp & 15;
    const int n   = (grp >> 4) & 7;
    const int b   = grp >> 7;

    const int p0   = sidx[0] + n * C_;
    const int qoff = j * 64 + w * 16;          // strip s covers q rows s*512 + qoff + 0..15

    const long bhbase = ((long)b * L_ + (long)n * C_) * HD_ + (long)h * D_;
    const int  tix    = (b * H_ + h) * NC_ + n;
    const _Float16* ktiles = ws + (long)tix * 32 * 2048;
    const _Float16* vtiles = ws + (long)NTILE * 2048 + (long)tix * 32 * 2048;

    // ---- Q fragments per strip, RoPE'd, f16, pre-scaled by log2(e) ----
    half8 aq[2][2];
    const int d0 = lg * 8;
    #pragma unroll
    for (int s = 0; s < 2; ++s) {
        const int qr = s * 512 + qoff + ln;
        const float* qp = qg + bhbase + (long)qr * HD_;
        float4 f0 = *(const float4*)(qp + d0);
        float4 f1 = *(const float4*)(qp + d0 + 4);
        float4 g0 = *(const float4*)(qp + d0 + 32);
        float4 g1 = *(const float4*)(qp + d0 + 36);
        float x[8] = {f0.x,f0.y,f0.z,f0.w,f1.x,f1.y,f1.z,f1.w};
        float y[8] = {g0.x,g0.y,g0.z,g0.w,g1.x,g1.y,g1.z,g1.w};
        const float pos = (float)(p0 + qr);
        #pragma unroll
        for (int jj = 0; jj < 8; ++jj) {
            float invf = fast_exp2(-(float)(d0 + jj) * LOG2B);
            float sn, cs; __sincosf(pos * invf, &sn, &cs);
            aq[s][0][jj] = (_Float16)((x[jj] * cs - y[jj] * sn) * LOG2E);
            aq[s][1][jj] = (_Float16)((y[jj] * cs + x[jj] * sn) * LOG2E);
        }
    }

    // ---- accumulators: O C-layout row=lg*4+r col=dt*16+ln; l,mr in q=ln space ----
    floatx4 O[2][4];
    float   l[2], mr[2];
    #pragma unroll
    for (int s = 0; s < 2; ++s) {
        l[s] = 0.f; mr[s] = -1e30f;
        #pragma unroll
        for (int dt = 0; dt < 4; ++dt) O[s][dt] = (floatx4){0.f,0.f,0.f,0.f};
    }

    // ---- cross-lane helper addresses (bytes = 4*src_lane) ----
    const int x32a   = (((t & 63) ^ 32) << 2);            // partner lane^32
    const int aA     = ((lg & 1) << 7) + (ln << 2);       // P-exchange source A = lane 16*(2*(lg&1))+ln
    const int aB     = aA + 64;                           // source B = A+16 lanes
    const int albase = lg << 4;                           // alpha/l gather: lanes lg*4+r

    // ---- staging roles (pure copy; swizzled LDS writes) ----
    const int skk = t >> 3;
    const int sdc = (t & 7) * 8;
    const int svd = t >> 2;
    const int svk = (t & 3) * 8;
    const int kwb = skk * 128 + ((sdc * 2) ^ ((skk & 7) << 4));
    const int vwb = svd * 64  + ((svk * 2) ^ (((svd >> 1) & 3) << 4));

    const int NKT = ((575 + j * 64) >> 5) + 1;            // block max q = 512+j*64+63
    int nkt_s[2];
    #pragma unroll
    for (int s = 0; s < 2; ++s) nkt_s[s] = ((s * 512 + qoff + 15) >> 5) + 1;

    // ---- prefetch tile 0 (2 x 16B per thread) ----
    half8 kreg = *(const half8*)(ktiles + (long)skk * 64 + sdc);
    half8 vreg = *(const half8*)(vtiles + (long)svd * 32 + svk);

    for (int kt = 0; kt < NKT; ++kt) {
        const int kb0 = kt * 32;
        __syncthreads();   // previous tile fully consumed
        *(half8*)((char*)KT + kwb) = kreg;
        *(half8*)((char*)VT + vwb) = vreg;
        if (kt + 1 < NKT) {
            const _Float16* kn = ktiles + (long)(kt + 1) * 2048;
            const _Float16* vn = vtiles + (long)(kt + 1) * 2048;
            kreg = *(const half8*)(kn + (long)skk * 64 + sdc);
            vreg = *(const half8*)(vn + (long)svd * 32 + svk);
        }
        __syncthreads();   // tile visible

        // ---- fragments shared across strips (swizzled reads) ----
        half8 bk0[2], bk1[2], bv[4];
        #pragma unroll
        for (int ct = 0; ct < 2; ++ct) {
            const int row = ct * 16 + ln;
            const char* base = (const char*)KT + row * 128;
            bk0[ct] = *(const half8*)(base + ((lg * 16)      ^ ((row & 7) << 4)));
            bk1[ct] = *(const half8*)(base + ((64 + lg * 16) ^ ((row & 7) << 4)));
        }
        #pragma unroll
        for (int dt = 0; dt < 4; ++dt) {
            const int dv = dt * 16 + ln;
            bv[dt] = *(const half8*)((const char*)VT + dv * 64 + ((lg * 16) ^ (((dv >> 1) & 3) << 4)));
        }

        #pragma unroll
        for (int s = 0; s < 2; ++s) {
            if (kt >= nkt_s[s]) continue;          // wave-uniform
            const int qs = s * 512 + qoff;

            // ---- swapped QK^T: sacc[ct][r] = S[k = kb0+ct*16+lg*4+r][q = qs+ln] ----
            floatx4 sacc[2];
            #pragma unroll
            for (int ct = 0; ct < 2; ++ct) {
                floatx4 acc = (floatx4){0.f,0.f,0.f,0.f};
                acc = __builtin_amdgcn_mfma_f32_16x16x32_f16(bk0[ct], aq[s][0], acc, 0, 0, 0);
                acc = __builtin_amdgcn_mfma_f32_16x16x32_f16(bk1[ct], aq[s][1], acc, 0, 0, 0);
                sacc[ct] = acc;
            }
            if (kb0 + 31 > qs) {                   // diagonal tile: mask k > q
                #pragma unroll
                for (int ct = 0; ct < 2; ++ct) {
                    const int kk = kb0 + ct * 16 + lg * 4;
                    #pragma unroll
                    for (int r = 0; r < 4; ++r)
                        if (kk + r > qs + ln) sacc[ct][r] = -1e30f;
                }
            }

            // ---- tile row-max for q=ln: in-lane tree + xor16 + xor32 ----
            float tm = fmaxf(fmaxf(fmaxf(sacc[0][0], sacc[0][1]), fmaxf(sacc[0][2], sacc[0][3])),
                             fmaxf(fmaxf(sacc[1][0], sacc[1][1]), fmaxf(sacc[1][2], sacc[1][3])));
            tm = fmaxf(tm, __int_as_float(__builtin_amdgcn_ds_swizzle(__float_as_int(tm), 0x401F)));
            tm = fmaxf(tm, __int_as_float(__builtin_amdgcn_ds_bpermute(x32a, __float_as_int(tm))));

            // ---- deferred-max rescale (rare) ----
            if (__any(tm > mr[s] + DTHR)) {
                float mnew  = fmaxf(mr[s], tm);
                float alpha = fast_exp2(mr[s] - mnew);
                mr[s] = mnew;
                l[s] *= alpha;
                float ar[4];
                #pragma unroll
                for (int r = 0; r < 4; ++r)
                    ar[r] = __int_as_float(__builtin_amdgcn_ds_bpermute(albase + 4 * r, __float_as_int(alpha)));
                #pragma unroll
                for (int dt = 0; dt < 4; ++dt)
                    #pragma unroll
                    for (int r = 0; r < 4; ++r) O[s][dt][r] *= ar[r];
            }

            // ---- P = exp2(S - m), row-sum, pack ----
            float p0v[4], p1v[4];
            #pragma unroll
            for (int r = 0; r < 4; ++r) {
                p0v[r] = fast_exp2(sacc[0][r] - mr[s]);
                p1v[r] = fast_exp2(sacc[1][r] - mr[s]);
            }
            float ts = ((p0v[0] + p0v[1]) + (p0v[2] + p0v[3]))
                     + ((p1v[0] + p1v[1]) + (p1v[2] + p1v[3]));
            ts += __int_as_float(__builtin_amdgcn_ds_swizzle(__float_as_int(ts), 0x401F));
            ts += __int_as_float(__builtin_amdgcn_ds_bpermute(x32a, __float_as_int(ts)));
            l[s] += ts;

            // ---- P^T -> A-fragment: ap[j] = P[q=ln][k=8*lg+j] via 8 bpermute ----
            // source dword d' holds k = (d'>>1)*16 + 4*lg' + 2*(d'&1) + {0,1}
            int pq0 = pk16(p0v[0], p0v[1]);
            int pq1 = pk16(p0v[2], p0v[3]);
            int pq2 = pk16(p1v[0], p1v[1]);
            int pq3 = pk16(p1v[2], p1v[3]);
            int bA0 = __builtin_amdgcn_ds_bpermute(aA, pq0);
            int bA1 = __builtin_amdgcn_ds_bpermute(aA, pq1);
            int bA2 = __builtin_amdgcn_ds_bpermute(aA, pq2);
            int bA3 = __builtin_amdgcn_ds_bpermute(aA, pq3);
            int bB0 = __builtin_amdgcn_ds_bpermute(aB, pq0);
            int bB1 = __builtin_amdgcn_ds_bpermute(aB, pq1);
            int bB2 = __builtin_amdgcn_ds_bpermute(aB, pq2);
            int bB3 = __builtin_amdgcn_ds_bpermute(aB, pq3);
            const bool hi = (lg >= 2);
            int4v apw;
            apw[0] = hi ? bA2 : bA0;
            apw[1] = hi ? bA3 : bA1;
            apw[2] = hi ? bB2 : bB0;
            apw[3] = hi ? bB3 : bB1;
            half8 ap = __builtin_bit_cast(half8, apw);

            #pragma unroll
            for (int dt = 0; dt < 4; ++dt)
                O[s][dt] = __builtin_amdgcn_mfma_f32_16x16x32_f16(ap, bv[dt], O[s][dt], 0, 0, 0);
        }
    }

    // ---- epilogue: gather 1/l from q=ln space to q=lg*4+r rows ----
    #pragma unroll
    for (int s = 0; s < 2; ++s) {
        const int qs = s * 512 + qoff;
        float li = 1.0f / l[s];
        float linv[4];
        #pragma unroll
        for (int r = 0; r < 4; ++r)
            linv[r] = __int_as_float(__builtin_amdgcn_ds_bpermute(albase + 4 * r, __float_as_int(li)));
        #pragma unroll
        for (int dt = 0; dt < 4; ++dt) {
            #pragma unroll
            for (int r = 0; r < 4; ++r) {
                const int qr = qs + lg * 4 + r;
                outg[bhbase + (long)qr * HD_ + dt * 16 + ln] = O[s][dt][r] * linv[r];
            }
        }
    }
}

extern "C" void kernel_launch(void* const* d_in, const int* in_sizes, int n_in,
                              void* d_out, int out_size, void* d_ws, size_t ws_size,
                              hipStream_t stream) {
    const float* q    = (const float*)d_in[0];
    const float* k    = (const float*)d_in[1];
    const float* v    = (const float*)d_in[2];
    const int*   sidx = (const int*)d_in[3];
    float*       out  = (float*)d_out;
    _Float16*    ws   = (_Float16*)d_ws;   // 64 MB (2 x 8192 tiles x 4 KB)

    dim3 block(256);
    prep_v7<<<dim3(NTILE), block, 0, stream>>>(k, v, sidx, ws);
    attn_v7<<<dim3(B_ * NC_ * H_ * 8), block, 0, stream>>>(q, sidx, ws, out);
}